// Round 15
// baseline (288.241 us; speedup 1.0000x reference)
//
#include <hip/hip_runtime.h>
#include <hip/hip_bf16.h>

typedef __attribute__((ext_vector_type(8))) short short8;
typedef __attribute__((ext_vector_type(4))) short s16x4;
typedef __attribute__((ext_vector_type(4))) float f32x4;
typedef __attribute__((ext_vector_type(4))) float float4v;

#define L 4096
#define CCH 128
#define NH 4
#define HD 32
#define NSB 4  // 2 streams * 2 batches
#define WQ_ELEMS 49152   // 3C*C per stream
#define WO_ELEMS 16384   // C*C per stream

static __device__ __forceinline__ unsigned short f2bf(float f) {
  unsigned int u = __float_as_uint(f);
  u += 0x7FFFu + ((u >> 16) & 1u);
  return (unsigned short)(u >> 16);
}

#if __has_builtin(__builtin_amdgcn_mfma_f32_16x16x16bf16_1k)
static __device__ __forceinline__ f32x4 mfma16(s16x4 a, s16x4 b, f32x4 c) {
  return __builtin_amdgcn_mfma_f32_16x16x16bf16_1k(a, b, c, 0, 0, 0);
}
#else
static __device__ __forceinline__ f32x4 mfma16(s16x4 a, s16x4 b, f32x4 c) {
  asm("v_mfma_f32_16x16x16_bf16 %0, %1, %2, %0"
      : "+v"(c) : "v"(a), "v"(b));
  return c;
}
#endif

// ---------------- Weight pre-convert: 128 blocks, f32 -> bf16 once ---------------
__global__ void __launch_bounds__(256) wconv_kernel(
    const float* __restrict__ wqA, const float* __restrict__ wqB,
    const float* __restrict__ woA, const float* __restrict__ woB,
    unsigned short* __restrict__ wq, unsigned short* __restrict__ wo) {
  int i = (blockIdx.x * 256 + threadIdx.x) * 4;
  const float* src;
  unsigned short* dst;
  if (i < WQ_ELEMS)            { src = wqA + i;                     dst = wq + i; }
  else if (i < 2 * WQ_ELEMS)   { src = wqB + (i - WQ_ELEMS);        dst = wq + i; }
  else if (i < 2 * WQ_ELEMS + WO_ELEMS)
                               { src = woA + (i - 2 * WQ_ELEMS);    dst = wo + (i - 2 * WQ_ELEMS); }
  else                         { src = woB + (i - 2 * WQ_ELEMS - WO_ELEMS);
                                 dst = wo + (i - 2 * WQ_ELEMS); }
  float4v v = *(const float4v*)src;
  s16x4 o;
  #pragma unroll
  for (int j = 0; j < 4; ++j) o[j] = (short)f2bf(v[j]);
  *(s16x4*)dst = o;
}

// ---------------- GN stats: 64 blocks (s*32 + b*16 + g), 256 thr -----------------
__global__ void __launch_bounds__(256) gn_stats_kernel(
    const float* __restrict__ xA, const float* __restrict__ xB,
    float* __restrict__ stats) {
  int bid = blockIdx.x;
  int g = bid & 15;
  int b = (bid >> 4) & 1;
  int s = bid >> 5;
  const float* x = s ? xB : xA;
  const float* xb = x + (size_t)b * CCH * L + (size_t)g * 8 * L;
  int t = threadIdx.x;
  float sum = 0.f, sq = 0.f;
  for (int e = t * 4; e < 8 * L; e += 1024) {
    float4v v = *(const float4v*)(xb + e);
    #pragma unroll
    for (int j = 0; j < 4; ++j) { sum += v[j]; sq += v[j] * v[j]; }
  }
  #pragma unroll
  for (int off = 32; off; off >>= 1) {
    sum += __shfl_down(sum, off);
    sq  += __shfl_down(sq, off);
  }
  __shared__ float red[2][4];
  int w = t >> 6, lane = t & 63;
  if (lane == 0) { red[0][w] = sum; red[1][w] = sq; }
  __syncthreads();
  if (t == 0) {
    float S = red[0][0] + red[0][1] + red[0][2] + red[0][3];
    float Q = red[1][0] + red[1][1] + red[1][2] + red[1][3];
    float mu = S * (1.f / 32768.f);
    float var = Q * (1.f / 32768.f) - mu * mu;
    stats[bid * 2] = mu;
    stats[bid * 2 + 1] = rsqrtf(var + 1e-5f);
  }
}

// ---------------- GN apply: 1024 blocks, 256 thr, 8 elem/thread ------------------
__global__ void __launch_bounds__(256) gn_apply_kernel(
    const float* __restrict__ xA, const float* __restrict__ xB,
    const float* __restrict__ gwA, const float* __restrict__ gbA,
    const float* __restrict__ gwB, const float* __restrict__ gbB,
    const float* __restrict__ stats,
    float* __restrict__ xn, unsigned short* __restrict__ xnT) {
  int i = (blockIdx.x * 256 + threadIdx.x) * 8;  // flat over [sb][c][l]
  int l = i & (L - 1);
  int c = (i >> 12) & 127;
  int sb = i >> 19;
  int s = sb >> 1, b = sb & 1, g = c >> 3;
  const float* x  = s ? xB : xA;
  const float* gw = s ? gwB : gwA;
  const float* gb = s ? gbB : gbA;
  float mu = stats[(sb * 16 + g) * 2];
  float rs = stats[(sb * 16 + g) * 2 + 1];
  float sc = rs * gw[c];
  float bi = gb[c] - mu * sc;
  const float* xp = x + (size_t)b * CCH * L + (size_t)c * L + l;
  float4v v0 = *(const float4v*)(xp);
  float4v v1 = *(const float4v*)(xp + 4);
  float r[8];
  #pragma unroll
  for (int j = 0; j < 4; ++j) { r[j] = v0[j] * sc + bi; r[4 + j] = v1[j] * sc + bi; }
  float* xo = xn + ((size_t)sb * CCH + c) * L + l;
  *(float4v*)(xo) = *(const float4v*)(r);
  *(float4v*)(xo + 4) = *(const float4v*)(r + 4);
  unsigned short* xt = xnT + ((size_t)sb * L + l) * CCH + c;
  #pragma unroll
  for (int j = 0; j < 8; ++j) xt[(size_t)j * CCH] = f2bf(r[j]);
}

// ---------------- QKV GEMM: grid NSB*24*64, 256 thr (4 waves, one 16x16 tile each) --
__global__ void __launch_bounds__(256, 4) qkv_kernel(
    const unsigned short* __restrict__ wqbf,
    const unsigned short* __restrict__ xnT,
    unsigned short* __restrict__ qT, unsigned short* __restrict__ kT,
    unsigned short* __restrict__ vv) {
  int bid = blockIdx.x;
  int nc = bid & 63;
  int mt = (bid >> 6) % 24;
  int sb = bid / (24 * 64);
  int s = sb >> 1;
  const unsigned short* wq = wqbf + (size_t)s * WQ_ELEMS;
  int t = threadIdx.x;
  int w = t >> 6, lane = t & 63, ln = lane & 15, sub = lane >> 4;
  int obase = mt * 16;
  int lbase = nc * 64 + w * 16;
  const unsigned short* bbase = xnT + ((size_t)sb * L + lbase + ln) * CCH;
  const unsigned short* abase = wq + (size_t)(obase + ln) * CCH;
  f32x4 acc = {0.f, 0.f, 0.f, 0.f};
  #pragma unroll
  for (int kc = 0; kc < 4; ++kc) {
    int k0 = kc * 32 + sub * 8;
    short8 af = *(const short8*)(abase + k0);
    short8 bfr = *(const short8*)(bbase + k0);
    acc = __builtin_amdgcn_mfma_f32_16x16x32_bf16(af, bfr, acc, 0, 0, 0);
  }
  const float qscale = 0.08838834764831845f;  // 1/sqrt(128)
  int lcol = lbase + ln;
  #pragma unroll
  for (int r = 0; r < 4; ++r) {
    int o = obase + sub * 4 + r;
    int head = o / 96;
    int rem = o - head * 96;
    int part = rem >> 5;
    int dd = rem & 31;
    size_t bh = (size_t)sb * NH + head;
    if (part == 0)      qT[(bh * L + lcol) * HD + dd] = f2bf(acc[r] * qscale);
    else if (part == 1) kT[(bh * L + lcol) * HD + dd] = f2bf(acc[r]);
    else                vv[(bh * HD + dd) * L + lcol] = f2bf(acc[r]);
  }
}

// ---------------- Flash attention: grid 512 blocks, 256 thr, reg-pipelined ----------
// 32 q-rows/wave (2 chains) + explicit register double-buffer prefetch of the next
// iteration's K/V fragments: loads for kt+1 are issued BEFORE computing kt, so the
// waitcnt before compute only drains loads issued one full iteration earlier.
struct KVfrag {
  short8 k0, k1, k2, k3;
  s16x4 v00, v01, v10, v11, v20, v21, v30, v31;
};

static __device__ __forceinline__ KVfrag load_kv(
    const unsigned short* kTb, const unsigned short* vb, int kbase, int ln, int sub) {
  KVfrag f;
  f.k0 = *(const short8*)(kTb + (size_t)(kbase +  0 + ln) * HD + sub * 8);
  f.k1 = *(const short8*)(kTb + (size_t)(kbase + 16 + ln) * HD + sub * 8);
  f.k2 = *(const short8*)(kTb + (size_t)(kbase + 32 + ln) * HD + sub * 8);
  f.k3 = *(const short8*)(kTb + (size_t)(kbase + 48 + ln) * HD + sub * 8);
  const unsigned short* v0 = vb + (size_t)ln * L + kbase + sub * 4;
  const unsigned short* v1 = vb + (size_t)(16 + ln) * L + kbase + sub * 4;
  f.v00 = *(const s16x4*)(v0);       f.v01 = *(const s16x4*)(v1);
  f.v10 = *(const s16x4*)(v0 + 16);  f.v11 = *(const s16x4*)(v1 + 16);
  f.v20 = *(const s16x4*)(v0 + 32);  f.v21 = *(const s16x4*)(v1 + 32);
  f.v30 = *(const s16x4*)(v0 + 48);  f.v31 = *(const s16x4*)(v1 + 48);
  return f;
}

__global__ void __launch_bounds__(256, 2) flash_kernel(
    const unsigned short* __restrict__ qT, const unsigned short* __restrict__ kT,
    const unsigned short* __restrict__ vv, unsigned short* __restrict__ ao) {
  int bid = blockIdx.x;
  int qt = bid & 31;
  int h  = (bid >> 5) & 3;
  int b  = (bid >> 7) & 1;
  int s  = bid >> 8;
  size_t bh_kv = (size_t)((s * 2 + b) * NH + h);
  size_t bh_q  = (size_t)(((s ^ 1) * 2 + b) * NH + h);
  const unsigned short* qTb = qT + bh_q * L * HD;
  const unsigned short* kTb = kT + bh_kv * L * HD;
  const unsigned short* vb  = vv + bh_kv * HD * L;

  int t = threadIdx.x;
  int w = t >> 6, lane = t & 63, ln = lane & 15, sub = lane >> 4;
  int qbase = qt * 128 + w * 32;

  short8 bq0 = *(const short8*)(qTb + (size_t)(qbase + ln) * HD + sub * 8);
  short8 bq1 = *(const short8*)(qTb + (size_t)(qbase + 16 + ln) * HD + sub * 8);

  f32x4 acc00 = {0.f, 0.f, 0.f, 0.f}, acc01 = {0.f, 0.f, 0.f, 0.f};
  f32x4 acc10 = {0.f, 0.f, 0.f, 0.f}, acc11 = {0.f, 0.f, 0.f, 0.f};
  float m0 = -1e30f, l0 = 0.f;
  float m1 = -1e30f, l1 = 0.f;

  const int NT = L / 64;
  KVfrag cur = load_kv(kTb, vb, 0, ln, sub);

  for (int kt = 0; kt < NT; ++kt) {
    // branch-free prefetch of the next tile (re-loads last tile on final iter)
    int nb = (kt + 1 < NT) ? (kt + 1) * 64 : kt * 64;
    KVfrag nxt = load_kv(kTb, vb, nb, ln, sub);

    f32x4 zz = {0.f, 0.f, 0.f, 0.f};
    f32x4 sa0 = __builtin_amdgcn_mfma_f32_16x16x32_bf16(cur.k0, bq0, zz, 0, 0, 0);
    f32x4 sa1 = __builtin_amdgcn_mfma_f32_16x16x32_bf16(cur.k1, bq0, zz, 0, 0, 0);
    f32x4 sa2 = __builtin_amdgcn_mfma_f32_16x16x32_bf16(cur.k2, bq0, zz, 0, 0, 0);
    f32x4 sa3 = __builtin_amdgcn_mfma_f32_16x16x32_bf16(cur.k3, bq0, zz, 0, 0, 0);
    f32x4 sb0 = __builtin_amdgcn_mfma_f32_16x16x32_bf16(cur.k0, bq1, zz, 0, 0, 0);
    f32x4 sb1 = __builtin_amdgcn_mfma_f32_16x16x32_bf16(cur.k1, bq1, zz, 0, 0, 0);
    f32x4 sb2 = __builtin_amdgcn_mfma_f32_16x16x32_bf16(cur.k2, bq1, zz, 0, 0, 0);
    f32x4 sb3 = __builtin_amdgcn_mfma_f32_16x16x32_bf16(cur.k3, bq1, zz, 0, 0, 0);

    // ---- softmax chain 0 ----
    s16x4 bp00, bp01, bp02, bp03;
    {
      float mx = fmaxf(fmaxf(sa0[0], sa0[1]), fmaxf(sa0[2], sa0[3]));
      mx = fmaxf(mx, fmaxf(fmaxf(sa1[0], sa1[1]), fmaxf(sa1[2], sa1[3])));
      mx = fmaxf(mx, fmaxf(fmaxf(sa2[0], sa2[1]), fmaxf(sa2[2], sa2[3])));
      mx = fmaxf(mx, fmaxf(fmaxf(sa3[0], sa3[1]), fmaxf(sa3[2], sa3[3])));
      mx = fmaxf(mx, __shfl_xor(mx, 16));
      mx = fmaxf(mx, __shfl_xor(mx, 32));
      float newm = fmaxf(m0, mx);
      float alpha = __expf(m0 - newm);
      float rsum = 0.f;
      #pragma unroll
      for (int r = 0; r < 4; ++r) {
        float p0 = __expf(sa0[r] - newm);
        float p1 = __expf(sa1[r] - newm);
        float p2 = __expf(sa2[r] - newm);
        float p3 = __expf(sa3[r] - newm);
        rsum += (p0 + p1) + (p2 + p3);
        bp00[r] = (short)f2bf(p0);
        bp01[r] = (short)f2bf(p1);
        bp02[r] = (short)f2bf(p2);
        bp03[r] = (short)f2bf(p3);
      }
      rsum += __shfl_xor(rsum, 16);
      rsum += __shfl_xor(rsum, 32);
      l0 = l0 * alpha + rsum;
      m0 = newm;
      #pragma unroll
      for (int r = 0; r < 4; ++r) { acc00[r] *= alpha; acc01[r] *= alpha; }
    }
    // ---- softmax chain 1 ----
    s16x4 bp10, bp11, bp12, bp13;
    {
      float mx = fmaxf(fmaxf(sb0[0], sb0[1]), fmaxf(sb0[2], sb0[3]));
      mx = fmaxf(mx, fmaxf(fmaxf(sb1[0], sb1[1]), fmaxf(sb1[2], sb1[3])));
      mx = fmaxf(mx, fmaxf(fmaxf(sb2[0], sb2[1]), fmaxf(sb2[2], sb2[3])));
      mx = fmaxf(mx, fmaxf(fmaxf(sb3[0], sb3[1]), fmaxf(sb3[2], sb3[3])));
      mx = fmaxf(mx, __shfl_xor(mx, 16));
      mx = fmaxf(mx, __shfl_xor(mx, 32));
      float newm = fmaxf(m1, mx);
      float alpha = __expf(m1 - newm);
      float rsum = 0.f;
      #pragma unroll
      for (int r = 0; r < 4; ++r) {
        float p0 = __expf(sb0[r] - newm);
        float p1 = __expf(sb1[r] - newm);
        float p2 = __expf(sb2[r] - newm);
        float p3 = __expf(sb3[r] - newm);
        rsum += (p0 + p1) + (p2 + p3);
        bp10[r] = (short)f2bf(p0);
        bp11[r] = (short)f2bf(p1);
        bp12[r] = (short)f2bf(p2);
        bp13[r] = (short)f2bf(p3);
      }
      rsum += __shfl_xor(rsum, 16);
      rsum += __shfl_xor(rsum, 32);
      l1 = l1 * alpha + rsum;
      m1 = newm;
      #pragma unroll
      for (int r = 0; r < 4; ++r) { acc10[r] *= alpha; acc11[r] *= alpha; }
    }
    // ---- PV both chains (V frags shared) ----
    acc00 = mfma16(cur.v00, bp00, acc00); acc01 = mfma16(cur.v01, bp00, acc01);
    acc00 = mfma16(cur.v10, bp01, acc00); acc01 = mfma16(cur.v11, bp01, acc01);
    acc00 = mfma16(cur.v20, bp02, acc00); acc01 = mfma16(cur.v21, bp02, acc01);
    acc00 = mfma16(cur.v30, bp03, acc00); acc01 = mfma16(cur.v31, bp03, acc01);
    acc10 = mfma16(cur.v00, bp10, acc10); acc11 = mfma16(cur.v01, bp10, acc11);
    acc10 = mfma16(cur.v10, bp11, acc10); acc11 = mfma16(cur.v11, bp11, acc11);
    acc10 = mfma16(cur.v20, bp12, acc10); acc11 = mfma16(cur.v21, bp12, acc11);
    acc10 = mfma16(cur.v30, bp13, acc10); acc11 = mfma16(cur.v31, bp13, acc11);

    cur = nxt;
  }

  // epilogue: normalize, write attn_out as [sb][L][C] bf16 (c = h*32 + d)
  {
    float inv = 1.0f / l0;
    int qrow = qbase + ln;
    size_t rowoff = ((size_t)(s * 2 + b) * L + qrow) * CCH + h * HD;
    s16x4 o0, o1;
    #pragma unroll
    for (int r = 0; r < 4; ++r) {
      o0[r] = (short)f2bf(acc00[r] * inv);
      o1[r] = (short)f2bf(acc01[r] * inv);
    }
    *(s16x4*)(ao + rowoff + sub * 4) = o0;
    *(s16x4*)(ao + rowoff + 16 + sub * 4) = o1;
  }
  {
    float inv = 1.0f / l1;
    int qrow = qbase + 16 + ln;
    size_t rowoff = ((size_t)(s * 2 + b) * L + qrow) * CCH + h * HD;
    s16x4 o0, o1;
    #pragma unroll
    for (int r = 0; r < 4; ++r) {
      o0[r] = (short)f2bf(acc10[r] * inv);
      o1[r] = (short)f2bf(acc11[r] * inv);
    }
    *(s16x4*)(ao + rowoff + sub * 4) = o0;
    *(s16x4*)(ao + rowoff + 16 + sub * 4) = o1;
  }
}

// ---------------- Out-proj GEMM + bias + residual: grid NSB*8*64, 256 thr -----------
__global__ void __launch_bounds__(256, 4) outproj_kernel(
    const unsigned short* __restrict__ wobf,
    const float* __restrict__ boA, const float* __restrict__ boB,
    const unsigned short* __restrict__ ao, const float* __restrict__ xn,
    float* __restrict__ out) {
  int bid = blockIdx.x;
  int nc = bid & 63;
  int mt = (bid >> 6) & 7;
  int sb = bid >> 9;
  int s = sb >> 1;
  int b = sb & 1;
  const unsigned short* wo = wobf + (size_t)s * WO_ELEMS;
  const float* bo = s ? boB : boA;
  int t = threadIdx.x;
  int w = t >> 6, lane = t & 63, ln = lane & 15, sub = lane >> 4;
  int obase = mt * 16;
  int lbase = nc * 64 + w * 16;
  const unsigned short* bbase = ao + ((size_t)sb * L + lbase + ln) * CCH;
  const unsigned short* abase = wo + (size_t)(obase + ln) * CCH;
  f32x4 acc = {0.f, 0.f, 0.f, 0.f};
  #pragma unroll
  for (int kc = 0; kc < 4; ++kc) {
    int k0 = kc * 32 + sub * 8;
    short8 af = *(const short8*)(abase + k0);
    short8 bfr = *(const short8*)(bbase + k0);
    acc = __builtin_amdgcn_mfma_f32_16x16x32_bf16(af, bfr, acc, 0, 0, 0);
  }
  int lcol = lbase + ln;
  #pragma unroll
  for (int r = 0; r < 4; ++r) {
    int o = obase + sub * 4 + r;
    out[(size_t)s * (2 * CCH * L) + ((size_t)b * CCH + o) * L + lcol] =
        acc[r] + bo[o] + xn[((size_t)sb * CCH + o) * L + lcol];
  }
}

extern "C" void kernel_launch(void* const* d_in, const int* in_sizes, int n_in,
                              void* d_out, int out_size, void* d_ws, size_t ws_size,
                              hipStream_t stream) {
  (void)in_sizes; (void)n_in; (void)out_size; (void)ws_size;
  const float* xA  = (const float*)d_in[0];
  const float* xB  = (const float*)d_in[1];
  const float* gwA = (const float*)d_in[2];
  const float* gbA = (const float*)d_in[3];
  const float* gwB = (const float*)d_in[4];
  const float* gbB = (const float*)d_in[5];
  const float* wqA = (const float*)d_in[6];
  const float* wqB = (const float*)d_in[7];
  const float* woA = (const float*)d_in[8];
  const float* boA = (const float*)d_in[9];
  const float* woB = (const float*)d_in[10];
  const float* boB = (const float*)d_in[11];
  float* out = (float*)d_out;

  char* ws = (char*)d_ws;
  size_t off = 0;
  float* xn = (float*)(ws + off);            off += (size_t)NSB * CCH * L * sizeof(float); // 8 MB
  unsigned short* xnT = (unsigned short*)(ws + off); off += (size_t)NSB * L * CCH * 2;     // 4 MB
  unsigned short* qT  = (unsigned short*)(ws + off); off += (size_t)NSB * NH * L * HD * 2; // 4 MB
  unsigned short* kT  = (unsigned short*)(ws + off); off += (size_t)NSB * NH * L * HD * 2; // 4 MB
  unsigned short* vv  = (unsigned short*)(ws + off); off += (size_t)NSB * NH * HD * L * 2; // 4 MB
  unsigned short* ao  = (unsigned short*)(ws + off); off += (size_t)NSB * L * CCH * 2;     // 4 MB
  float* stats = (float*)(ws + off);         off += 64 * 2 * sizeof(float);
  unsigned short* wqbf = (unsigned short*)(ws + off); off += (size_t)2 * WQ_ELEMS * 2;     // 192 KB
  unsigned short* wobf = (unsigned short*)(ws + off); off += (size_t)2 * WO_ELEMS * 2;     // 64 KB

  wconv_kernel<<<dim3(128), dim3(256), 0, stream>>>(wqA, wqB, woA, woB, wqbf, wobf);
  gn_stats_kernel<<<dim3(64), dim3(256), 0, stream>>>(xA, xB, stats);
  gn_apply_kernel<<<dim3(1024), dim3(256), 0, stream>>>(xA, xB, gwA, gbA, gwB, gbB,
                                                        stats, xn, xnT);
  qkv_kernel<<<dim3(NSB * 24 * 64), dim3(256), 0, stream>>>(wqbf, xnT, qT, kT, vv);
  flash_kernel<<<dim3(512), dim3(256), 0, stream>>>(qT, kT, vv, ao);
  outproj_kernel<<<dim3(NSB * 8 * 64), dim3(256), 0, stream>>>(wobf, boA, boB, ao, xn, out);
}

// Round 16
// 245.055 us; speedup vs baseline: 1.1762x; 1.1762x over previous
//
#include <hip/hip_runtime.h>
#include <hip/hip_bf16.h>

typedef __attribute__((ext_vector_type(8))) short short8;
typedef __attribute__((ext_vector_type(4))) short s16x4;
typedef __attribute__((ext_vector_type(4))) float f32x4;
typedef __attribute__((ext_vector_type(4))) float float4v;

#define L 4096
#define CCH 128
#define NH 4
#define HD 32
#define NSB 4  // 2 streams * 2 batches
#define WQ_ELEMS 49152   // 3C*C per stream
#define WO_ELEMS 16384   // C*C per stream

static __device__ __forceinline__ unsigned short f2bf(float f) {
  unsigned int u = __float_as_uint(f);
  u += 0x7FFFu + ((u >> 16) & 1u);
  return (unsigned short)(u >> 16);
}

#if __has_builtin(__builtin_amdgcn_mfma_f32_16x16x16bf16_1k)
static __device__ __forceinline__ f32x4 mfma16(s16x4 a, s16x4 b, f32x4 c) {
  return __builtin_amdgcn_mfma_f32_16x16x16bf16_1k(a, b, c, 0, 0, 0);
}
#else
static __device__ __forceinline__ f32x4 mfma16(s16x4 a, s16x4 b, f32x4 c) {
  asm("v_mfma_f32_16x16x16_bf16 %0, %1, %2, %0"
      : "+v"(c) : "v"(a), "v"(b));
  return c;
}
#endif

// ---------------- Weight pre-convert: 128 blocks, f32 -> bf16 once ---------------
__global__ void __launch_bounds__(256) wconv_kernel(
    const float* __restrict__ wqA, const float* __restrict__ wqB,
    const float* __restrict__ woA, const float* __restrict__ woB,
    unsigned short* __restrict__ wq, unsigned short* __restrict__ wo) {
  int i = (blockIdx.x * 256 + threadIdx.x) * 4;
  const float* src;
  unsigned short* dst;
  if (i < WQ_ELEMS)            { src = wqA + i;                     dst = wq + i; }
  else if (i < 2 * WQ_ELEMS)   { src = wqB + (i - WQ_ELEMS);        dst = wq + i; }
  else if (i < 2 * WQ_ELEMS + WO_ELEMS)
                               { src = woA + (i - 2 * WQ_ELEMS);    dst = wo + (i - 2 * WQ_ELEMS); }
  else                         { src = woB + (i - 2 * WQ_ELEMS - WO_ELEMS);
                                 dst = wo + (i - 2 * WQ_ELEMS); }
  float4v v = *(const float4v*)src;
  s16x4 o;
  #pragma unroll
  for (int j = 0; j < 4; ++j) o[j] = (short)f2bf(v[j]);
  *(s16x4*)dst = o;
}

// ---------------- GN stats: 64 blocks (s*32 + b*16 + g), 256 thr -----------------
__global__ void __launch_bounds__(256) gn_stats_kernel(
    const float* __restrict__ xA, const float* __restrict__ xB,
    float* __restrict__ stats) {
  int bid = blockIdx.x;
  int g = bid & 15;
  int b = (bid >> 4) & 1;
  int s = bid >> 5;
  const float* x = s ? xB : xA;
  const float* xb = x + (size_t)b * CCH * L + (size_t)g * 8 * L;
  int t = threadIdx.x;
  float sum = 0.f, sq = 0.f;
  for (int e = t * 4; e < 8 * L; e += 1024) {
    float4v v = *(const float4v*)(xb + e);
    #pragma unroll
    for (int j = 0; j < 4; ++j) { sum += v[j]; sq += v[j] * v[j]; }
  }
  #pragma unroll
  for (int off = 32; off; off >>= 1) {
    sum += __shfl_down(sum, off);
    sq  += __shfl_down(sq, off);
  }
  __shared__ float red[2][4];
  int w = t >> 6, lane = t & 63;
  if (lane == 0) { red[0][w] = sum; red[1][w] = sq; }
  __syncthreads();
  if (t == 0) {
    float S = red[0][0] + red[0][1] + red[0][2] + red[0][3];
    float Q = red[1][0] + red[1][1] + red[1][2] + red[1][3];
    float mu = S * (1.f / 32768.f);
    float var = Q * (1.f / 32768.f) - mu * mu;
    stats[bid * 2] = mu;
    stats[bid * 2 + 1] = rsqrtf(var + 1e-5f);
  }
}

// ---------------- GN apply: 1024 blocks, 256 thr, 8 elem/thread ------------------
__global__ void __launch_bounds__(256) gn_apply_kernel(
    const float* __restrict__ xA, const float* __restrict__ xB,
    const float* __restrict__ gwA, const float* __restrict__ gbA,
    const float* __restrict__ gwB, const float* __restrict__ gbB,
    const float* __restrict__ stats,
    float* __restrict__ xn, unsigned short* __restrict__ xnT) {
  int i = (blockIdx.x * 256 + threadIdx.x) * 8;  // flat over [sb][c][l]
  int l = i & (L - 1);
  int c = (i >> 12) & 127;
  int sb = i >> 19;
  int s = sb >> 1, b = sb & 1, g = c >> 3;
  const float* x  = s ? xB : xA;
  const float* gw = s ? gwB : gwA;
  const float* gb = s ? gbB : gbA;
  float mu = stats[(sb * 16 + g) * 2];
  float rs = stats[(sb * 16 + g) * 2 + 1];
  float sc = rs * gw[c];
  float bi = gb[c] - mu * sc;
  const float* xp = x + (size_t)b * CCH * L + (size_t)c * L + l;
  float4v v0 = *(const float4v*)(xp);
  float4v v1 = *(const float4v*)(xp + 4);
  float r[8];
  #pragma unroll
  for (int j = 0; j < 4; ++j) { r[j] = v0[j] * sc + bi; r[4 + j] = v1[j] * sc + bi; }
  float* xo = xn + ((size_t)sb * CCH + c) * L + l;
  *(float4v*)(xo) = *(const float4v*)(r);
  *(float4v*)(xo + 4) = *(const float4v*)(r + 4);
  unsigned short* xt = xnT + ((size_t)sb * L + l) * CCH + c;
  #pragma unroll
  for (int j = 0; j < 8; ++j) xt[(size_t)j * CCH] = f2bf(r[j]);
}

// ---------------- QKV GEMM: grid NSB*24*64, 256 thr (4 waves, one 16x16 tile each) --
__global__ void __launch_bounds__(256, 4) qkv_kernel(
    const unsigned short* __restrict__ wqbf,
    const unsigned short* __restrict__ xnT,
    unsigned short* __restrict__ qT, unsigned short* __restrict__ kT,
    unsigned short* __restrict__ vv) {
  int bid = blockIdx.x;
  int nc = bid & 63;
  int mt = (bid >> 6) % 24;
  int sb = bid / (24 * 64);
  int s = sb >> 1;
  const unsigned short* wq = wqbf + (size_t)s * WQ_ELEMS;
  int t = threadIdx.x;
  int w = t >> 6, lane = t & 63, ln = lane & 15, sub = lane >> 4;
  int obase = mt * 16;
  int lbase = nc * 64 + w * 16;
  const unsigned short* bbase = xnT + ((size_t)sb * L + lbase + ln) * CCH;
  const unsigned short* abase = wq + (size_t)(obase + ln) * CCH;
  f32x4 acc = {0.f, 0.f, 0.f, 0.f};
  #pragma unroll
  for (int kc = 0; kc < 4; ++kc) {
    int k0 = kc * 32 + sub * 8;
    short8 af = *(const short8*)(abase + k0);
    short8 bfr = *(const short8*)(bbase + k0);
    acc = __builtin_amdgcn_mfma_f32_16x16x32_bf16(af, bfr, acc, 0, 0, 0);
  }
  const float qscale = 0.08838834764831845f;  // 1/sqrt(128)
  int lcol = lbase + ln;
  #pragma unroll
  for (int r = 0; r < 4; ++r) {
    int o = obase + sub * 4 + r;
    int head = o / 96;
    int rem = o - head * 96;
    int part = rem >> 5;
    int dd = rem & 31;
    size_t bh = (size_t)sb * NH + head;
    if (part == 0)      qT[(bh * L + lcol) * HD + dd] = f2bf(acc[r] * qscale);
    else if (part == 1) kT[(bh * L + lcol) * HD + dd] = f2bf(acc[r]);
    else                vv[(bh * HD + dd) * L + lcol] = f2bf(acc[r]);
  }
}

// ---------------- Flash attention: grid 512 blocks, 256 thr, LDS-staged -------------
// K/V tile (64 keys) staged once per block into LDS in FRAGMENT-MAJOR layout via
// register staging (load global at iter top, ds_write at iter bottom -> HBM/L2
// latency hides under compute; sched_barrier pins the loads early). Compute reads
// are contiguous wave-wide ds_read_b128/b64 (conflict-free). Double-buffered LDS.
// XCD-aware bid swizzle: 32 blocks sharing one head's K/V co-reside per XCD L2.
__global__ void __launch_bounds__(256, 2) flash_kernel(
    const unsigned short* __restrict__ qT, const unsigned short* __restrict__ kT,
    const unsigned short* __restrict__ vv, unsigned short* __restrict__ ao) {
  int bid0 = blockIdx.x;
  int bid = (bid0 & 7) * 64 + (bid0 >> 3);  // bijective: 512 = 8 * 64
  int qt = bid & 31;
  int h  = (bid >> 5) & 3;
  int b  = (bid >> 7) & 1;
  int s  = bid >> 8;
  size_t bh_kv = (size_t)((s * 2 + b) * NH + h);
  size_t bh_q  = (size_t)(((s ^ 1) * 2 + b) * NH + h);
  const unsigned short* qTb = qT + bh_q * L * HD;
  const unsigned short* kTb = kT + bh_kv * L * HD;
  const unsigned short* vb  = vv + bh_kv * HD * L;

  int t = threadIdx.x;
  int w = t >> 6, lane = t & 63, ln = lane & 15, sub = lane >> 4;
  int qbase = qt * 128 + w * 32;

  __shared__ unsigned short lds_k[2][2048];  // frag-major: [tt][sub][ln][8]
  __shared__ unsigned short lds_v[2][2048];  // frag-major: [tt][half][sub][ln][4]

  // ---- staging coordinates (wave w stages 1KB of K + 1KB of V) ----
  // K: lane handles frag (tt=w, sub=lane&3, ln=lane>>2) = K[16w+(lane>>2)][8*(lane&3)..]
  const unsigned short* gK = kTb + (size_t)(w * 16 + (lane >> 2)) * HD + (lane & 3) * 8;
  int dstK = ((w * 4 + (lane & 3)) * 16 + (lane >> 2)) * 8;
  // V: lane handles 16B = V[d=8w+(lane>>3)][8*(lane&7)..] -> two 8B frags
  int dV = w * 8 + (lane >> 3);
  const unsigned short* gV = vb + (size_t)dV * L + (lane & 7) * 8;
  int ttv = (lane & 7) >> 1, halfv = w >> 1, lnv = (w & 1) * 8 + (lane >> 3);
  int sub0 = ((lane & 7) & 1) * 2;
  int dstV0 = (((ttv * 2 + halfv) * 4 + sub0) * 16 + lnv) * 4;

  // Q B-frags for the two chains (pre-scaled by 1/sqrt(128) in qkv)
  short8 bq0 = *(const short8*)(qTb + (size_t)(qbase + ln) * HD + sub * 8);
  short8 bq1 = *(const short8*)(qTb + (size_t)(qbase + 16 + ln) * HD + sub * 8);

  // prologue: stage tile 0 into buf 0
  {
    short8 sk = *(const short8*)(gK);
    short8 sv = *(const short8*)(gV);
    s16x4 svlo, svhi;
    #pragma unroll
    for (int j = 0; j < 4; ++j) { svlo[j] = sv[j]; svhi[j] = sv[4 + j]; }
    *(short8*)&lds_k[0][dstK] = sk;
    *(s16x4*)&lds_v[0][dstV0] = svlo;
    *(s16x4*)&lds_v[0][dstV0 + 64] = svhi;
  }
  __syncthreads();

  f32x4 acc00 = {0.f, 0.f, 0.f, 0.f}, acc01 = {0.f, 0.f, 0.f, 0.f};
  f32x4 acc10 = {0.f, 0.f, 0.f, 0.f}, acc11 = {0.f, 0.f, 0.f, 0.f};
  float m0 = -1e30f, l0 = 0.f;
  float m1 = -1e30f, l1 = 0.f;

  const int NT = L / 64;
  for (int kt = 0; kt < NT; ++kt) {
    int cur = kt & 1;
    // issue next-tile staging loads NOW; consumed by ds_write after compute
    int nk = (kt + 1 < NT) ? kt + 1 : kt;
    short8 sk = *(const short8*)(gK + (size_t)nk * 2048);
    short8 sv = *(const short8*)(gV + nk * 64);
    __builtin_amdgcn_sched_barrier(0);  // pin loads above the compute

    // ---- compute from lds[cur] ----
    short8 ak0 = *(const short8*)&lds_k[cur][((0 * 4 + sub) * 16 + ln) * 8];
    short8 ak1 = *(const short8*)&lds_k[cur][((1 * 4 + sub) * 16 + ln) * 8];
    short8 ak2 = *(const short8*)&lds_k[cur][((2 * 4 + sub) * 16 + ln) * 8];
    short8 ak3 = *(const short8*)&lds_k[cur][((3 * 4 + sub) * 16 + ln) * 8];
    f32x4 zz = {0.f, 0.f, 0.f, 0.f};
    f32x4 sa0 = __builtin_amdgcn_mfma_f32_16x16x32_bf16(ak0, bq0, zz, 0, 0, 0);
    f32x4 sa1 = __builtin_amdgcn_mfma_f32_16x16x32_bf16(ak1, bq0, zz, 0, 0, 0);
    f32x4 sa2 = __builtin_amdgcn_mfma_f32_16x16x32_bf16(ak2, bq0, zz, 0, 0, 0);
    f32x4 sa3 = __builtin_amdgcn_mfma_f32_16x16x32_bf16(ak3, bq0, zz, 0, 0, 0);
    f32x4 sb0 = __builtin_amdgcn_mfma_f32_16x16x32_bf16(ak0, bq1, zz, 0, 0, 0);
    f32x4 sb1 = __builtin_amdgcn_mfma_f32_16x16x32_bf16(ak1, bq1, zz, 0, 0, 0);
    f32x4 sb2 = __builtin_amdgcn_mfma_f32_16x16x32_bf16(ak2, bq1, zz, 0, 0, 0);
    f32x4 sb3 = __builtin_amdgcn_mfma_f32_16x16x32_bf16(ak3, bq1, zz, 0, 0, 0);

    // ---- softmax chain 0 ----
    s16x4 bp00, bp01, bp02, bp03;
    {
      float mx = fmaxf(fmaxf(sa0[0], sa0[1]), fmaxf(sa0[2], sa0[3]));
      mx = fmaxf(mx, fmaxf(fmaxf(sa1[0], sa1[1]), fmaxf(sa1[2], sa1[3])));
      mx = fmaxf(mx, fmaxf(fmaxf(sa2[0], sa2[1]), fmaxf(sa2[2], sa2[3])));
      mx = fmaxf(mx, fmaxf(fmaxf(sa3[0], sa3[1]), fmaxf(sa3[2], sa3[3])));
      mx = fmaxf(mx, __shfl_xor(mx, 16));
      mx = fmaxf(mx, __shfl_xor(mx, 32));
      float newm = fmaxf(m0, mx);
      float alpha = __expf(m0 - newm);
      float rsum = 0.f;
      #pragma unroll
      for (int r = 0; r < 4; ++r) {
        float p0 = __expf(sa0[r] - newm);
        float p1 = __expf(sa1[r] - newm);
        float p2 = __expf(sa2[r] - newm);
        float p3 = __expf(sa3[r] - newm);
        rsum += (p0 + p1) + (p2 + p3);
        bp00[r] = (short)f2bf(p0);
        bp01[r] = (short)f2bf(p1);
        bp02[r] = (short)f2bf(p2);
        bp03[r] = (short)f2bf(p3);
      }
      rsum += __shfl_xor(rsum, 16);
      rsum += __shfl_xor(rsum, 32);
      l0 = l0 * alpha + rsum;
      m0 = newm;
      #pragma unroll
      for (int r = 0; r < 4; ++r) { acc00[r] *= alpha; acc01[r] *= alpha; }
    }
    // ---- softmax chain 1 ----
    s16x4 bp10, bp11, bp12, bp13;
    {
      float mx = fmaxf(fmaxf(sb0[0], sb0[1]), fmaxf(sb0[2], sb0[3]));
      mx = fmaxf(mx, fmaxf(fmaxf(sb1[0], sb1[1]), fmaxf(sb1[2], sb1[3])));
      mx = fmaxf(mx, fmaxf(fmaxf(sb2[0], sb2[1]), fmaxf(sb2[2], sb2[3])));
      mx = fmaxf(mx, fmaxf(fmaxf(sb3[0], sb3[1]), fmaxf(sb3[2], sb3[3])));
      mx = fmaxf(mx, __shfl_xor(mx, 16));
      mx = fmaxf(mx, __shfl_xor(mx, 32));
      float newm = fmaxf(m1, mx);
      float alpha = __expf(m1 - newm);
      float rsum = 0.f;
      #pragma unroll
      for (int r = 0; r < 4; ++r) {
        float p0 = __expf(sb0[r] - newm);
        float p1 = __expf(sb1[r] - newm);
        float p2 = __expf(sb2[r] - newm);
        float p3 = __expf(sb3[r] - newm);
        rsum += (p0 + p1) + (p2 + p3);
        bp10[r] = (short)f2bf(p0);
        bp11[r] = (short)f2bf(p1);
        bp12[r] = (short)f2bf(p2);
        bp13[r] = (short)f2bf(p3);
      }
      rsum += __shfl_xor(rsum, 16);
      rsum += __shfl_xor(rsum, 32);
      l1 = l1 * alpha + rsum;
      m1 = newm;
      #pragma unroll
      for (int r = 0; r < 4; ++r) { acc10[r] *= alpha; acc11[r] *= alpha; }
    }
    // ---- PV both chains (V frags from LDS, shared) ----
    #pragma unroll
    for (int tt = 0; tt < 4; ++tt) {
      s16x4 av0 = *(const s16x4*)&lds_v[cur][(((tt * 2 + 0) * 4 + sub) * 16 + ln) * 4];
      s16x4 av1 = *(const s16x4*)&lds_v[cur][(((tt * 2 + 1) * 4 + sub) * 16 + ln) * 4];
      s16x4 bpa = (tt == 0) ? bp00 : (tt == 1) ? bp01 : (tt == 2) ? bp02 : bp03;
      s16x4 bpb = (tt == 0) ? bp10 : (tt == 1) ? bp11 : (tt == 2) ? bp12 : bp13;
      acc00 = mfma16(av0, bpa, acc00); acc01 = mfma16(av1, bpa, acc01);
      acc10 = mfma16(av0, bpb, acc10); acc11 = mfma16(av1, bpb, acc11);
    }

    // ---- write staged next tile into the other buffer, then sync ----
    {
      s16x4 svlo, svhi;
      #pragma unroll
      for (int j = 0; j < 4; ++j) { svlo[j] = sv[j]; svhi[j] = sv[4 + j]; }
      *(short8*)&lds_k[cur ^ 1][dstK] = sk;
      *(s16x4*)&lds_v[cur ^ 1][dstV0] = svlo;
      *(s16x4*)&lds_v[cur ^ 1][dstV0 + 64] = svhi;
    }
    __syncthreads();
  }

  // epilogue: normalize, write attn_out as [sb][L][C] bf16 (c = h*32 + d)
  {
    float inv = 1.0f / l0;
    int qrow = qbase + ln;
    size_t rowoff = ((size_t)(s * 2 + b) * L + qrow) * CCH + h * HD;
    s16x4 o0, o1;
    #pragma unroll
    for (int r = 0; r < 4; ++r) {
      o0[r] = (short)f2bf(acc00[r] * inv);
      o1[r] = (short)f2bf(acc01[r] * inv);
    }
    *(s16x4*)(ao + rowoff + sub * 4) = o0;
    *(s16x4*)(ao + rowoff + 16 + sub * 4) = o1;
  }
  {
    float inv = 1.0f / l1;
    int qrow = qbase + 16 + ln;
    size_t rowoff = ((size_t)(s * 2 + b) * L + qrow) * CCH + h * HD;
    s16x4 o0, o1;
    #pragma unroll
    for (int r = 0; r < 4; ++r) {
      o0[r] = (short)f2bf(acc10[r] * inv);
      o1[r] = (short)f2bf(acc11[r] * inv);
    }
    *(s16x4*)(ao + rowoff + sub * 4) = o0;
    *(s16x4*)(ao + rowoff + 16 + sub * 4) = o1;
  }
}

// ---------------- Out-proj GEMM + bias + residual: grid NSB*8*64, 256 thr -----------
__global__ void __launch_bounds__(256, 4) outproj_kernel(
    const unsigned short* __restrict__ wobf,
    const float* __restrict__ boA, const float* __restrict__ boB,
    const unsigned short* __restrict__ ao, const float* __restrict__ xn,
    float* __restrict__ out) {
  int bid = blockIdx.x;
  int nc = bid & 63;
  int mt = (bid >> 6) & 7;
  int sb = bid >> 9;
  int s = sb >> 1;
  int b = sb & 1;
  const unsigned short* wo = wobf + (size_t)s * WO_ELEMS;
  const float* bo = s ? boB : boA;
  int t = threadIdx.x;
  int w = t >> 6, lane = t & 63, ln = lane & 15, sub = lane >> 4;
  int obase = mt * 16;
  int lbase = nc * 64 + w * 16;
  const unsigned short* bbase = ao + ((size_t)sb * L + lbase + ln) * CCH;
  const unsigned short* abase = wo + (size_t)(obase + ln) * CCH;
  f32x4 acc = {0.f, 0.f, 0.f, 0.f};
  #pragma unroll
  for (int kc = 0; kc < 4; ++kc) {
    int k0 = kc * 32 + sub * 8;
    short8 af = *(const short8*)(abase + k0);
    short8 bfr = *(const short8*)(bbase + k0);
    acc = __builtin_amdgcn_mfma_f32_16x16x32_bf16(af, bfr, acc, 0, 0, 0);
  }
  int lcol = lbase + ln;
  #pragma unroll
  for (int r = 0; r < 4; ++r) {
    int o = obase + sub * 4 + r;
    out[(size_t)s * (2 * CCH * L) + ((size_t)b * CCH + o) * L + lcol] =
        acc[r] + bo[o] + xn[((size_t)sb * CCH + o) * L + lcol];
  }
}

extern "C" void kernel_launch(void* const* d_in, const int* in_sizes, int n_in,
                              void* d_out, int out_size, void* d_ws, size_t ws_size,
                              hipStream_t stream) {
  (void)in_sizes; (void)n_in; (void)out_size; (void)ws_size;
  const float* xA  = (const float*)d_in[0];
  const float* xB  = (const float*)d_in[1];
  const float* gwA = (const float*)d_in[2];
  const float* gbA = (const float*)d_in[3];
  const float* gwB = (const float*)d_in[4];
  const float* gbB = (const float*)d_in[5];
  const float* wqA = (const float*)d_in[6];
  const float* wqB = (const float*)d_in[7];
  const float* woA = (const float*)d_in[8];
  const float* boA = (const float*)d_in[9];
  const float* woB = (const float*)d_in[10];
  const float* boB = (const float*)d_in[11];
  float* out = (float*)d_out;

  char* ws = (char*)d_ws;
  size_t off = 0;
  float* xn = (float*)(ws + off);            off += (size_t)NSB * CCH * L * sizeof(float); // 8 MB
  unsigned short* xnT = (unsigned short*)(ws + off); off += (size_t)NSB * L * CCH * 2;     // 4 MB
  unsigned short* qT  = (unsigned short*)(ws + off); off += (size_t)NSB * NH * L * HD * 2; // 4 MB
  unsigned short* kT  = (unsigned short*)(ws + off); off += (size_t)NSB * NH * L * HD * 2; // 4 MB
  unsigned short* vv  = (unsigned short*)(ws + off); off += (size_t)NSB * NH * HD * L * 2; // 4 MB
  unsigned short* ao  = (unsigned short*)(ws + off); off += (size_t)NSB * L * CCH * 2;     // 4 MB
  float* stats = (float*)(ws + off);         off += 64 * 2 * sizeof(float);
  unsigned short* wqbf = (unsigned short*)(ws + off); off += (size_t)2 * WQ_ELEMS * 2;     // 192 KB
  unsigned short* wobf = (unsigned short*)(ws + off); off += (size_t)2 * WO_ELEMS * 2;     // 64 KB

  wconv_kernel<<<dim3(128), dim3(256), 0, stream>>>(wqA, wqB, woA, woB, wqbf, wobf);
  gn_stats_kernel<<<dim3(64), dim3(256), 0, stream>>>(xA, xB, stats);
  gn_apply_kernel<<<dim3(1024), dim3(256), 0, stream>>>(xA, xB, gwA, gbA, gwB, gbB,
                                                        stats, xn, xnT);
  qkv_kernel<<<dim3(NSB * 24 * 64), dim3(256), 0, stream>>>(wqbf, xnT, qT, kT, vv);
  flash_kernel<<<dim3(512), dim3(256), 0, stream>>>(qT, kT, vv, ao);
  outproj_kernel<<<dim3(NSB * 8 * 64), dim3(256), 0, stream>>>(wobf, boA, boB, ao, xn, out);
}